// Round 1
// 1381.864 us; speedup vs baseline: 1.2418x; 1.2418x over previous
//
#include <hip/hip_runtime.h>

#define DEV __device__ __forceinline__

#define Dd   64
#define Bb   1024
#define Mm   32
#define Kk   16
#define Ll   8
#define NKGk 65536
#define NH   32768            // B*M
#define ROWS (NH + 2*Bb)      // 34816

// ---- workspace layout (float offsets) ----
#define OFF_WTATT   0          // 64x64  transposed W_tatt
#define OFF_WGS     4096       // 64x64  transposed W_gatt[:, :64]   (WgsT[j*64+d] = W_gatt[d][j])
#define OFF_WCOMB   8192       // 128x64 transposed (W_gatt[:,64:] @ W_re)
#define OFF_WRE     16384      // 128x64 transposed W_re
#define OFF_WAGG    24576      // 128x64 transposed W_agg (WaggT[j*64+d] = W_agg[d][j], j<128)
#define OFF_WU      32768      // 192x64 transposed W_u_mlp
#define OFF_GVEC    45056      // 64     sigmoid(gate)
#define OFF_USERG   45120      // 1024x64
#define OFF_UATT    110656     // 1024x64
#define OFF_SELFH   176192     // 32768x64
#define OFF_HISLC   2273344    // 32768x64
#define OFF_HISGB   4370496    // 32768x64
#define OFF_SELFPN  6467648    // 2x1024x64 (pos, then neg)
#define OFF_LCPN    6598720    // 2x1024x64
#define OFF_GBPN    6729792    // 2x1024x64
#define OFF_ULCPN   6860864    // 2x1024x128
#define OFF_KGSUM   7123008    // 1
#define OFF_KGS     7123012    // 2x65536 kg squared distances (pos, neg)
// GRU packed-weight tables OVERLAY the KGS scratch region: prep writes them,
// gru3 reads them, and only afterwards does kg2 overwrite the region with
// distances (same stream => ordering guaranteed, every launch re-preps).
#define OFF_WIHP    7123072    // 16x8x(4x3x8) = 12288  W_ih packed [jc][w][jj][gate][oi]
#define OFF_WHHP    7135360    // 12288                 W_hh packed, same layout
#define OFF_WAGP    7147648    // 32x8x(4x8)   = 8192   W_agg packed [jc][w][jj][oi]

DEV float4 ld4(const float* p){ return *reinterpret_cast<const float4*>(p); }
DEV void st4(float* p, const float4 v){ *reinterpret_cast<float4*>(p) = v; }

DEV float tanh_fast(float x){
  float cx = fminf(15.f, fmaxf(-15.f, x));
  float e = __expf(2.f*cx);
  return __fdividef(e - 1.f, e + 1.f);
}
DEV float sigmoid_fast(float x){ return __fdividef(1.f, 1.f + __expf(-x)); }

// acc[d] += W^T rows (4 consecutive) dotted against a float4 of x.
#define MV4(ACC_, W_, X4_) \
  { _Pragma("unroll") for (int d_ = 0; d_ < 64; ++d_) ACC_[d_] += (W_)[d_]       * (X4_).x; \
    _Pragma("unroll") for (int d_ = 0; d_ < 64; ++d_) ACC_[d_] += (W_)[64 + d_]  * (X4_).y; \
    _Pragma("unroll") for (int d_ = 0; d_ < 64; ++d_) ACC_[d_] += (W_)[128 + d_] * (X4_).z; \
    _Pragma("unroll") for (int d_ = 0; d_ < 64; ++d_) ACC_[d_] += (W_)[192 + d_] * (X4_).w; }

// ---------------- prep: weight transposes, Wcomb fold, gate sigmoid, GRU packs ----------------
__global__ void prep_kernel(const float* __restrict__ W_tatt, const float* __restrict__ W_gatt,
                            const float* __restrict__ W_re, const float* __restrict__ W_agg,
                            const float* __restrict__ W_u, const float* __restrict__ W_ih,
                            const float* __restrict__ W_hh, const float* __restrict__ gate,
                            float* __restrict__ ws)
{
  int t = threadIdx.x;
  for (int i = t; i < 4096; i += 256){
    int d = i >> 6, j = i & 63;
    ws[OFF_WTATT + j*64 + d] = W_tatt[i];            // W_tatt (64,64)
    ws[OFF_WGS   + j*64 + d] = W_gatt[d*128 + j];    // self half of W_gatt
  }
  for (int i = t; i < 8192; i += 256){
    int j = i >> 6, d = i & 63;
    ws[OFF_WRE  + i] = W_re[d*128 + j];
    ws[OFF_WAGG + i] = W_agg[d*128 + j];
    float s = 0.f;
    for (int dp = 0; dp < 64; ++dp) s += W_gatt[d*128 + 64 + dp] * W_re[dp*128 + j];
    ws[OFF_WCOMB + i] = s;                           // (W_gatt[:,64:] @ W_re)^T
  }
  for (int i = t; i < 12288; i += 256){
    int j = i >> 6, d = i & 63;
    ws[OFF_WU + i] = W_u[d*192 + j];
  }
  // GRU gate-weight pack: linear i = ((jc*8+w)*96) + jj*24 + g*8 + oi ;  j=jc*4+jj, o=g*64+w*8+oi
  for (int i = t; i < 12288; i += 256){
    int jc = i / 768, r1 = i - jc*768;
    int ww = r1 / 96,  r2 = r1 - ww*96;
    int jj = r2 / 24,  r3 = r2 - jj*24;
    int g = r3 >> 3,   oi = r3 & 7;
    int j = jc*4 + jj, o = g*64 + ww*8 + oi;
    ws[OFF_WIHP + i] = W_ih[o*64 + j];
    ws[OFF_WHHP + i] = W_hh[o*64 + j];
  }
  // GRU epilogue W_agg pack: i = ((jc*8+w)*32) + jj*8 + oi ; j=jc*4+jj (0..127), o=w*8+oi
  for (int i = t; i < 8192; i += 256){
    int jc = i >> 8, r1 = i & 255;
    int ww = r1 >> 5, r2 = r1 & 31;
    int jj = r2 >> 3, oi = r2 & 7;
    ws[OFF_WAGP + i] = W_agg[(ww*8 + oi)*128 + jc*4 + jj];
  }
  if (t < 64) ws[OFF_GVEC + t] = sigmoid_fast(gate[t]);
}

// ---------------- user gather + u_att = relu(user_g @ W_tatt^T + b_tatt) ----------------
__global__ void user_prep_kernel(const int* __restrict__ uidx, const float* __restrict__ user_emb,
                                 const float* __restrict__ b_tatt, float* __restrict__ ws)
{
  int gid = blockIdx.x*256 + threadIdx.x;
  int b = gid >> 6, lane = gid & 63;
  long ui = uidx[b];
  float ugd = user_emb[ui*64 + lane];
  ws[OFF_USERG + b*64 + lane] = ugd;
  const float* WtT = ws + OFF_WTATT;
  float acc = b_tatt[lane];
  for (int j = 0; j < 64; ++j) acc += WtT[j*64 + lane] * __shfl(ugd, j);
  ws[OFF_UATT + b*64 + lane] = fmaxf(acc, 0.f);
}

// ---------------- agg_lc v2: thread = (row, k); 16 rows x 16 k per block ----------------
__global__ __launch_bounds__(256) void agg2_kernel(
  const int* __restrict__ hS, const int* __restrict__ hN, const int* __restrict__ hR,
  const int* __restrict__ pS, const int* __restrict__ pN, const int* __restrict__ pR,
  const int* __restrict__ nS, const int* __restrict__ nN, const int* __restrict__ nR,
  const float* __restrict__ entity, const float* __restrict__ relation,
  const float* __restrict__ b_gatt, const float* __restrict__ b_agg,
  float* __restrict__ ws)
{
  int tid = threadIdx.x;
  int k = tid & 15, rl = tid >> 4;          // k-lane, row-in-block
  int rbase = blockIdx.x*16;
  const int *sI, *nI, *rI; float *sO, *aO; int nb0, uhis;
  if (rbase < NH)          { sI=hS; nI=hN; rI=hR; sO=ws+OFF_SELFH;        aO=ws+OFF_HISLC;       nb0=rbase;        uhis=1; }
  else if (rbase < NH+Bb)  { sI=pS; nI=pN; rI=pR; sO=ws+OFF_SELFPN;       aO=ws+OFF_LCPN;       nb0=rbase-NH;     uhis=0; }
  else                     { sI=nS; nI=nN; rI=nR; sO=ws+OFF_SELFPN+65536; aO=ws+OFF_LCPN+65536; nb0=rbase-NH-Bb;  uhis=0; }
  int n = nb0 + rl;
  int urow = uhis ? (n >> 5) : n;

  const float* es = entity + (long)sI[n]*64;
  const float* WgsT = ws + OFF_WGS;
  float4 sc4 = ld4(b_gatt + k*4);
  for (int j4 = 0; j4 < 16; ++j4){
    float4 s4 = ld4(es + 4*j4);
    float4 w0 = ld4(WgsT + (4*j4+0)*64 + k*4);
    float4 w1 = ld4(WgsT + (4*j4+1)*64 + k*4);
    float4 w2 = ld4(WgsT + (4*j4+2)*64 + k*4);
    float4 w3 = ld4(WgsT + (4*j4+3)*64 + k*4);
    sc4.x += w0.x*s4.x + w1.x*s4.y + w2.x*s4.z + w3.x*s4.w;
    sc4.y += w0.y*s4.x + w1.y*s4.y + w2.y*s4.z + w3.y*s4.w;
    sc4.z += w0.z*s4.x + w1.z*s4.y + w2.z*s4.z + w3.z*s4.w;
    sc4.w += w0.w*s4.x + w1.w*s4.y + w2.w*s4.z + w3.w*s4.w;
  }
  st4(sO + (long)n*64 + k*4, ld4(es + k*4));

  long nbI = nI[n*16 + k], rlI = rI[n*16 + k];
  const float* en = entity + nbI*64;
  const float* er = relation + rlI*64;
  float xnb[64];
  #pragma unroll
  for (int j4 = 0; j4 < 16; ++j4){
    float4 x4 = ld4(en + 4*j4);
    xnb[4*j4+0] = x4.x; xnb[4*j4+1] = x4.y; xnb[4*j4+2] = x4.z; xnb[4*j4+3] = x4.w;
  }
  float acc[64];
  #pragma unroll
  for (int d = 0; d < 64; ++d) acc[d] = 0.f;
  const float* WcT = ws + OFF_WCOMB;
  for (int j4 = 0; j4 < 16; ++j4){
    float4 x4 = ld4(en + 4*j4);
    MV4(acc, WcT + j4*256, x4);
  }
  for (int j4 = 0; j4 < 16; ++j4){
    float4 x4 = ld4(er + 4*j4);
    MV4(acc, WcT + 4096 + j4*256, x4);
  }
  int gl = (tid & 63) & 48;
  const float* up = ws + OFF_UATT + (long)urow*64;
  float lg = 0.f;
  #pragma unroll
  for (int j4 = 0; j4 < 16; ++j4){
    float4 u4 = ld4(up + 4*j4);
    float s0 = __shfl(sc4.x, gl + j4);
    float s1 = __shfl(sc4.y, gl + j4);
    float s2 = __shfl(sc4.z, gl + j4);
    float s3 = __shfl(sc4.w, gl + j4);
    lg += u4.x*tanh_fast(acc[4*j4+0] + s0);
    lg += u4.y*tanh_fast(acc[4*j4+1] + s1);
    lg += u4.z*tanh_fast(acc[4*j4+2] + s2);
    lg += u4.w*tanh_fast(acc[4*j4+3] + s3);
  }
  float mx = lg;
  mx = fmaxf(mx, __shfl_xor(mx, 1)); mx = fmaxf(mx, __shfl_xor(mx, 2));
  mx = fmaxf(mx, __shfl_xor(mx, 4)); mx = fmaxf(mx, __shfl_xor(mx, 8));
  float e = __expf(lg - mx);
  float se = e;
  se += __shfl_xor(se, 1); se += __shfl_xor(se, 2);
  se += __shfl_xor(se, 4); se += __shfl_xor(se, 8);
  float att = __fdividef(e, se);
  const float* WaT = ws + OFF_WAGG;
  float4 a4 = ld4(b_agg + k*4);
  for (int j4 = 0; j4 < 16; ++j4){
    float4 s4 = ld4(es + 4*j4);
    float4 w0 = ld4(WaT + (4*j4+0)*64 + k*4);
    float4 w1 = ld4(WaT + (4*j4+1)*64 + k*4);
    float4 w2 = ld4(WaT + (4*j4+2)*64 + k*4);
    float4 w3 = ld4(WaT + (4*j4+3)*64 + k*4);
    a4.x += w0.x*s4.x + w1.x*s4.y + w2.x*s4.z + w3.x*s4.w;
    a4.y += w0.y*s4.x + w1.y*s4.y + w2.y*s4.z + w3.y*s4.w;
    a4.z += w0.z*s4.x + w1.z*s4.y + w2.z*s4.z + w3.z*s4.w;
    a4.w += w0.w*s4.x + w1.w*s4.y + w2.w*s4.z + w3.w*s4.w;
  }
  #pragma unroll
  for (int j = 0; j < 64; ++j){
    float v = att * xnb[j];
    v += __shfl_xor(v, 1); v += __shfl_xor(v, 2);
    v += __shfl_xor(v, 4); v += __shfl_xor(v, 8);
    float4 wv = ld4(WaT + (64+j)*64 + k*4);
    a4.x += wv.x*v; a4.y += wv.y*v; a4.z += wv.z*v; a4.w += wv.w*v;
  }
  float t0 = tanh_fast(a4.x), t1 = tanh_fast(a4.y), t2 = tanh_fast(a4.z), t3 = tanh_fast(a4.w);
  float ss = t0*t0 + t1*t1 + t2*t2 + t3*t3;
  ss += __shfl_xor(ss, 1); ss += __shfl_xor(ss, 2);
  ss += __shfl_xor(ss, 4); ss += __shfl_xor(ss, 8);
  float rn = __fdividef(1.f, fmaxf(sqrtf(ss), 1e-12f));
  float4 o4; o4.x = t0*rn; o4.y = t1*rn; o4.z = t2*rn; o4.w = t3*rn;
  st4(aO + (long)n*64 + k*4, o4);
}

// ---------------- GRU v6: j-outer/i-inner, packed scalar weights, LDS x staging ----------------
// Round-0 (this session) analysis: v5 was LDS/lgkm-latency-bound (VALUBusy 36%, 512 ds_read
// per wave per t, x gather latency exposed at t-top). v6:
//  * loop interchange: per j read h once, feed 8 outputs x 3 gates (24 FMA/read) -> 8x less LDS
//  * weights pre-packed [jc][w][...] in ws -> contiguous wave-uniform s_load_dwordx16 stream
//  * x in LDS [dim][row] (conflict-free), staged per-t; global gather issued BEFORE the h-pass,
//    LDS write deferred until after it (T14 split) so ~500cy gather latency hides under ~3000cy FMA
//  * path index software-pipelined one t ahead; t=0 h-pass skipped (h==0), no zero-init
//  * [..][65] pad kills the 8-way conflict in the normalize remap
// VGPR target <=85 (48 accs + temps) so LDS (49920B) allows 3 blocks/CU.
__global__ __launch_bounds__(512) void gru3_kernel(
  const int* __restrict__ hS, const int* __restrict__ hP,
  const int* __restrict__ pS, const int* __restrict__ pP,
  const int* __restrict__ nS, const int* __restrict__ nP,
  const float* __restrict__ entity,
  const float* __restrict__ b_ih, const float* __restrict__ b_hh,
  const float* __restrict__ b_agg,
  float* __restrict__ ws)
{
  __shared__ float hb[2][64][65];           // double-buffered h, [buf][dim][row]
  __shared__ float xb[64][65];              // per-t x staging / epilogue self rows, [dim][row]
  int tid = threadIdx.x;
  int w = __builtin_amdgcn_readfirstlane(tid >> 6);   // wave id 0..7 (uniform)
  int lane = tid & 63;                                // lane = row
  int rbase = blockIdx.x*64;
  const int *sIv, *pIv; float* aO; int nb0;
  if (rbase < NH)          { sIv=hS; pIv=hP; aO=ws+OFF_HISGB;        nb0=rbase; }
  else if (rbase < NH+Bb)  { sIv=pS; pIv=pP; aO=ws+OFF_GBPN;        nb0=rbase-NH; }
  else                     { sIv=nS; pIv=nP; aO=ws+OFF_GBPN+65536;  nb0=rbase-NH-Bb; }
  int o0 = w*8;                                       // this wave's output dims o0..o0+7
  const float* WIHP = ws + OFF_WIHP;
  const float* WHHP = ws + OFF_WHHP;
  const float* WAGP = ws + OFF_WAGP;

  // uniform biases (s_loads, compiler hoists)
  float bir[8], biz[8], bin_[8], bhr[8], bhz[8], bhn[8];
  #pragma unroll
  for (int i = 0; i < 8; ++i){
    bir[i] = b_ih[o0+i]; biz[i] = b_ih[64+o0+i]; bin_[i] = b_ih[128+o0+i];
    bhr[i] = b_hh[o0+i]; bhz[i] = b_hh[64+o0+i]; bhn[i]  = b_hh[128+o0+i];
  }

  int pt_next = pIv[(nb0 + lane)*8];        // path index pipelined one t ahead
  #pragma unroll 1
  for (int t = 0; t < 8; ++t){
    // issue x gather for this t (consumed after the h-pass)
    const float* ex = entity + (long)pt_next*64 + o0;
    float4 xa = ld4(ex), xc = ld4(ex + 4);
    if (t < 7) pt_next = pIv[(nb0 + lane)*8 + t + 1];

    int cur = t & 1, nxt = cur ^ 1;
    float ahr[8], ahz[8], ahn[8];
    #pragma unroll
    for (int i = 0; i < 8; ++i){ ahr[i] = bhr[i]; ahz[i] = bhz[i]; ahn[i] = bhn[i]; }
    if (t){                                 // h == 0 at t=0: gh = b_hh only
      #pragma unroll 2
      for (int jc = 0; jc < 16; ++jc){
        const float* wp = WHHP + (jc*8 + w)*96;
        float h0 = hb[cur][4*jc+0][lane];
        float h1 = hb[cur][4*jc+1][lane];
        float h2 = hb[cur][4*jc+2][lane];
        float h3 = hb[cur][4*jc+3][lane];
        #pragma unroll
        for (int i = 0; i < 8; ++i){
          ahr[i] += wp[   i]*h0 + wp[24+i]*h1 + wp[48+i]*h2 + wp[72+i]*h3;
          ahz[i] += wp[ 8+i]*h0 + wp[32+i]*h1 + wp[56+i]*h2 + wp[80+i]*h3;
          ahn[i] += wp[16+i]*h0 + wp[40+i]*h1 + wp[64+i]*h2 + wp[88+i]*h3;
        }
      }
    }
    // stage x (gather latency hidden by h-pass); [dim][row], lane-stride 4B = conflict-free
    xb[o0+0][lane]=xa.x; xb[o0+1][lane]=xa.y; xb[o0+2][lane]=xa.z; xb[o0+3][lane]=xa.w;
    xb[o0+4][lane]=xc.x; xb[o0+5][lane]=xc.y; xb[o0+6][lane]=xc.z; xb[o0+7][lane]=xc.w;
    __syncthreads();                        // A: xb staged by all waves; hb[cur] reads done

    float air[8], aiz[8], ain[8];
    #pragma unroll
    for (int i = 0; i < 8; ++i){ air[i] = bir[i]; aiz[i] = biz[i]; ain[i] = bin_[i]; }
    #pragma unroll 2
    for (int jc = 0; jc < 16; ++jc){
      const float* wp = WIHP + (jc*8 + w)*96;
      float x0 = xb[4*jc+0][lane];
      float x1 = xb[4*jc+1][lane];
      float x2 = xb[4*jc+2][lane];
      float x3 = xb[4*jc+3][lane];
      #pragma unroll
      for (int i = 0; i < 8; ++i){
        air[i] += wp[   i]*x0 + wp[24+i]*x1 + wp[48+i]*x2 + wp[72+i]*x3;
        aiz[i] += wp[ 8+i]*x0 + wp[32+i]*x1 + wp[56+i]*x2 + wp[80+i]*x3;
        ain[i] += wp[16+i]*x0 + wp[40+i]*x1 + wp[64+i]*x2 + wp[88+i]*x3;
      }
    }
    #pragma unroll
    for (int i = 0; i < 8; ++i){
      float r  = sigmoid_fast(air[i] + ahr[i]);
      float z  = sigmoid_fast(aiz[i] + ahz[i]);
      float nn = tanh_fast(ain[i] + r*ahn[i]);
      float hp = t ? hb[cur][o0+i][lane] : 0.f;   // value-select, safe to speculate
      hb[nxt][o0+i][lane] = (1.f - z)*nn + z*hp;
    }
    __syncthreads();                        // B: h_new ready; xb reads done before next stage
  }

  // ---- epilogue: agg = normalize(tanh(W_agg@[self|hT]+b_agg)); final h is in hb[0] ----
  long si = sIv[nb0 + lane];
  const float* es = entity + si*64 + o0;
  float4 aa = ld4(es), cc = ld4(es + 4);    // self gather in flight during h-part below
  float ag[8];
  #pragma unroll
  for (int i = 0; i < 8; ++i) ag[i] = b_agg[o0+i];
  #pragma unroll 2
  for (int jc = 16; jc < 32; ++jc){         // hT half first (hides self gather)
    const float* wp = WAGP + (jc*8 + w)*32;
    float h0 = hb[0][4*(jc-16)+0][lane];
    float h1 = hb[0][4*(jc-16)+1][lane];
    float h2 = hb[0][4*(jc-16)+2][lane];
    float h3 = hb[0][4*(jc-16)+3][lane];
    #pragma unroll
    for (int i = 0; i < 8; ++i)
      ag[i] += wp[i]*h0 + wp[8+i]*h1 + wp[16+i]*h2 + wp[24+i]*h3;
  }
  xb[o0+0][lane]=aa.x; xb[o0+1][lane]=aa.y; xb[o0+2][lane]=aa.z; xb[o0+3][lane]=aa.w;
  xb[o0+4][lane]=cc.x; xb[o0+5][lane]=cc.y; xb[o0+6][lane]=cc.z; xb[o0+7][lane]=cc.w;
  __syncthreads();
  #pragma unroll 2
  for (int jc = 0; jc < 16; ++jc){          // self half
    const float* wp = WAGP + (jc*8 + w)*32;
    float x0 = xb[4*jc+0][lane];
    float x1 = xb[4*jc+1][lane];
    float x2 = xb[4*jc+2][lane];
    float x3 = xb[4*jc+3][lane];
    #pragma unroll
    for (int i = 0; i < 8; ++i)
      ag[i] += wp[i]*x0 + wp[8+i]*x1 + wp[16+i]*x2 + wp[24+i]*x3;
  }
  #pragma unroll
  for (int i = 0; i < 8; ++i) hb[1][o0+i][lane] = tanh_fast(ag[i]);
  __syncthreads();
  // normalize + coalesced store: thread (q = tid&7 dims-chunk, r = tid>>3 row)
  int q = tid & 7, r = tid >> 3;
  float vv[8];
  float ss = 0.f;
  #pragma unroll
  for (int jj = 0; jj < 8; ++jj){ float v = hb[1][q*8+jj][r]; vv[jj] = v; ss += v*v; }
  ss += __shfl_xor(ss, 1); ss += __shfl_xor(ss, 2); ss += __shfl_xor(ss, 4);
  float rn = __fdividef(1.f, fmaxf(sqrtf(ss), 1e-12f));
  int n2 = nb0 + r;
  #pragma unroll
  for (int jj4 = 0; jj4 < 2; ++jj4){
    float4 o4; o4.x = vv[4*jj4]*rn; o4.y = vv[4*jj4+1]*rn; o4.z = vv[4*jj4+2]*rn; o4.w = vv[4*jj4+3]*rn;
    st4(aO + (long)n2*64 + q*8 + 4*jj4, o4);
  }
}

// ---------------- KG v2: thread = (r, branch); store squared distances ----------------
__global__ __launch_bounds__(256) void kg2_kernel(
  const int* __restrict__ kh, const int* __restrict__ kr,
  const int* __restrict__ kt, const int* __restrict__ ktn,
  const float* __restrict__ entity, const float* __restrict__ relation,
  float* __restrict__ ws)
{
  int tid = threadIdx.x;
  int br = blockIdx.x >> 8;
  int r  = (blockIdx.x & 255)*256 + tid;
  const int* tailI = br ? ktn : kt;
  const float* WreT = ws + OFF_WRE;
  const float* er = relation + (long)kr[r]*64;
  const float* et = entity + (long)tailI[r]*64;
  float acc[64];
  #pragma unroll
  for (int d = 0; d < 64; ++d) acc[d] = 0.f;
  for (int j4 = 0; j4 < 16; ++j4){
    float4 x4 = ld4(et + 4*j4);
    MV4(acc, WreT + j4*256, x4);
  }
  for (int j4 = 0; j4 < 16; ++j4){
    float4 x4 = ld4(er + 4*j4);
    MV4(acc, WreT + 4096 + j4*256, x4);
  }
  const float* eh = entity + (long)kh[r]*64;
  float s = 0.f;
  #pragma unroll
  for (int j4 = 0; j4 < 16; ++j4){
    float4 h4 = ld4(eh + 4*j4);
    float d0 = h4.x - acc[4*j4+0], d1 = h4.y - acc[4*j4+1];
    float d2 = h4.z - acc[4*j4+2], d3 = h4.w - acc[4*j4+3];
    s += d0*d0 + d1*d1 + d2*d2 + d3*d3;
  }
  ws[OFF_KGS + br*65536 + r] = s;
}

__global__ void kg_reduce_kernel(float* __restrict__ ws)
{
  int r = blockIdx.x*256 + threadIdx.x;
  float s  = ws[OFF_KGS + r];
  float sn = ws[OFF_KGS + 65536 + r];
  float dif = sn - s;
  float ls = fminf(dif, 0.f) - __logf(1.f + __expf(-fabsf(dif)));
  #pragma unroll
  for (int m2 = 1; m2 < 64; m2 <<= 1) ls += __shfl_xor(ls, m2);
  if ((threadIdx.x & 63) == 0) atomicAdd(ws + OFF_KGSUM, ls);
}

// ---------------- rs_att: one wave per (b, branch) ----------------
__global__ void rsatt_kernel(const float* __restrict__ W_iatt, const float* __restrict__ b_iatt,
                             float* __restrict__ ws)
{
  int gid = blockIdx.x*256 + threadIdx.x;
  int gw = gid >> 6, lane = gid & 63;
  int b = gw >> 1, br = gw & 1;
  const float* selfB = ws + OFF_SELFPN + br*65536 + b*64;
  const float* lcB   = ws + OFF_LCPN   + br*65536 + b*64;
  const float* gbB   = ws + OFF_GBPN   + br*65536 + b*64;
  const float* gvec  = ws + OFF_GVEC;
  const float* selfH = ws + OFF_SELFH;
  const float* hisLC = ws + OFF_HISLC;
  const float* hisGB = ws + OFF_HISGB;

  float gd = gvec[lane];
  float sv = selfB[lane], lcv = lcB[lane], gbv = gbB[lane];
  float gated = gd*lcv + (1.f - gd)*gbv;
  float part = W_iatt[128+lane]*sv + W_iatt[192+lane]*gated;
  #pragma unroll
  for (int m2 = 1; m2 < 64; m2 <<= 1) part += __shfl_xor(part, m2);
  float itemdot = part + b_iatt[0];

  int m = lane & 31, half = lane >> 5;
  long nrow = (long)(b*32 + m)*64;
  float sh = 0.f;
  if (half == 0){
    for (int j4 = 0; j4 < 16; ++j4){
      float4 h4 = ld4(selfH + nrow + 4*j4);
      float4 w4 = ld4(W_iatt + 4*j4);
      sh += w4.x*h4.x + w4.y*h4.y + w4.z*h4.z + w4.w*h4.w;
    }
  } else {
    for (int j4 = 0; j4 < 16; ++j4){
      float4 l4 = ld4(hisLC + nrow + 4*j4);
      float4 g4 = ld4(hisGB + nrow + 4*j4);
      float4 gg = ld4(gvec + 4*j4);
      float4 w4 = ld4(W_iatt + 64 + 4*j4);
      sh += w4.x*(gg.x*l4.x + (1.f-gg.x)*g4.x);
      sh += w4.y*(gg.y*l4.y + (1.f-gg.y)*g4.y);
      sh += w4.z*(gg.z*l4.z + (1.f-gg.z)*g4.z);
      sh += w4.w*(gg.w*l4.w + (1.f-gg.w)*g4.w);
    }
  }
  sh += __shfl_xor(sh, 32);
  float logit = tanh_fast(sh + itemdot);
  float mxv = logit;
  #pragma unroll
  for (int m2 = 1; m2 < 32; m2 <<= 1) mxv = fmaxf(mxv, __shfl_xor(mxv, m2));
  float e = __expf(logit - mxv);
  float se = e;
  #pragma unroll
  for (int m2 = 1; m2 < 32; m2 <<= 1) se += __shfl_xor(se, m2);
  float att = __fdividef(e, se);

  float u1 = 0.f, u2 = 0.f;
  for (int mm = 0; mm < 32; ++mm){
    float a = __shfl(att, mm);
    long nr = (long)(b*32 + mm)*64;
    float x1 = selfH[nr + lane];
    float x2 = gd*hisLC[nr + lane] + (1.f - gd)*hisGB[nr + lane];
    u1 += a*x1; u2 += a*x2;
  }
  float* upo = ws + OFF_ULCPN + (long)(br*1024 + b)*128;
  upo[lane] = u1; upo[64 + lane] = u2;
}

// ---------------- u-MLP + score: one wave per (b, branch) ----------------
__global__ void umlp_kernel(const float* __restrict__ b_u, float* __restrict__ ws, float* __restrict__ out)
{
  int gid = blockIdx.x*256 + threadIdx.x;
  int gw = gid >> 6, lane = gid & 63;
  int b = gw >> 1, br = gw & 1;
  const float* WuT = ws + OFF_WU;
  const float* ug  = ws + OFF_USERG + b*64;
  const float* ul  = ws + OFF_ULCPN + (long)(br*1024 + b)*128;
  float acc = b_u[lane];
  for (int j = 0; j < 64; ++j)  acc += WuT[j*64 + lane] * ug[j];
  for (int j = 0; j < 128; ++j) acc += WuT[(64 + j)*64 + lane] * ul[j];
  float uo = fmaxf(acc, 0.f);
  float ssv = uo*uo;
  #pragma unroll
  for (int m2 = 1; m2 < 64; m2 <<= 1) ssv += __shfl_xor(ssv, m2);
  float rn = __fdividef(1.f, fmaxf(sqrtf(ssv), 1e-12f));
  float nuo = uo*rn;
  const float* selfB = ws + OFF_SELFPN + br*65536 + b*64;
  const float* lcB   = ws + OFF_LCPN   + br*65536 + b*64;
  const float* gbB   = ws + OFF_GBPN   + br*65536 + b*64;
  float gd = ws[OFF_GVEC + lane];
  float gated = gd*lcB[lane] + (1.f - gd)*gbB[lane];
  float p = ug[lane]*selfB[lane] + nuo*gated;
  #pragma unroll
  for (int m2 = 1; m2 < 64; m2 <<= 1) p += __shfl_xor(p, m2);
  if (lane == 0) out[br*1024 + b] = p;
}

// ---------------- final loss ----------------
__global__ void loss_kernel(const float* __restrict__ ws, float* __restrict__ out)
{
  __shared__ float red[16];
  int t = threadIdx.x;
  float ps = out[t], ns_ = out[1024 + t];
  float dif = ps - ns_;
  float v = fminf(dif, 0.f) - __logf(1.f + __expf(-fabsf(dif)));
  #pragma unroll
  for (int m2 = 1; m2 < 64; m2 <<= 1) v += __shfl_xor(v, m2);
  if ((t & 63) == 0) red[t >> 6] = v;
  __syncthreads();
  if (t == 0){
    float s = 0.f;
    for (int i = 0; i < 16; ++i) s += red[i];
    float rs = -s * (1.f/1024.f);
    float kg = -ws[OFF_KGSUM] * (1.f/65536.f);
    out[2048] = rs + kg;
  }
}

extern "C" void kernel_launch(void* const* d_in, const int* in_sizes, int n_in,
                              void* d_out, int out_size, void* d_ws, size_t ws_size,
                              hipStream_t stream)
{
  const int* user_indices = (const int*)d_in[0];
  const int* ent_his_self = (const int*)d_in[1];
  const int* ent_his_nbr  = (const int*)d_in[2];
  const int* rel_his      = (const int*)d_in[3];
  const int* ent_pos_self = (const int*)d_in[4];
  const int* ent_pos_nbr  = (const int*)d_in[5];
  const int* rel_pos      = (const int*)d_in[6];
  const int* ent_neg_self = (const int*)d_in[7];
  const int* ent_neg_nbr  = (const int*)d_in[8];
  const int* rel_neg      = (const int*)d_in[9];
  const int* gb_his_self  = (const int*)d_in[10];
  const int* gb_his_path  = (const int*)d_in[11];
  const int* gb_pos_self  = (const int*)d_in[12];
  const int* gb_pos_path  = (const int*)d_in[13];
  const int* gb_neg_self  = (const int*)d_in[14];
  const int* gb_neg_path  = (const int*)d_in[15];
  const int* kg_head      = (const int*)d_in[16];
  const int* kg_rel       = (const int*)d_in[17];
  const int* kg_tail      = (const int*)d_in[18];
  const int* kg_tail_neg  = (const int*)d_in[19];
  const float* entity_emb   = (const float*)d_in[20];
  const float* relation_emb = (const float*)d_in[21];
  const float* user_emb     = (const float*)d_in[22];
  const float* gate         = (const float*)d_in[23];
  const float* W_u_mlp      = (const float*)d_in[24];
  const float* b_u_mlp      = (const float*)d_in[25];
  const float* W_re         = (const float*)d_in[26];
  const float* W_agg        = (const float*)d_in[27];
  const float* b_agg        = (const float*)d_in[28];
  const float* W_gatt       = (const float*)d_in[29];
  const float* b_gatt       = (const float*)d_in[30];
  const float* W_iatt       = (const float*)d_in[31];
  const float* b_iatt       = (const float*)d_in[32];
  const float* W_tatt       = (const float*)d_in[33];
  const float* b_tatt       = (const float*)d_in[34];
  const float* W_ih         = (const float*)d_in[35];
  const float* W_hh         = (const float*)d_in[36];
  const float* b_ih         = (const float*)d_in[37];
  const float* b_hh         = (const float*)d_in[38];
  float* ws  = (float*)d_ws;
  float* out = (float*)d_out;

  (void)hipMemsetAsync(ws + OFF_KGSUM, 0, sizeof(float), stream);
  prep_kernel<<<1, 256, 0, stream>>>(W_tatt, W_gatt, W_re, W_agg, W_u_mlp, W_ih, W_hh, gate, ws);
  user_prep_kernel<<<256, 256, 0, stream>>>(user_indices, user_emb, b_tatt, ws);
  agg2_kernel<<<ROWS/16, 256, 0, stream>>>(
      ent_his_self, ent_his_nbr, rel_his,
      ent_pos_self, ent_pos_nbr, rel_pos,
      ent_neg_self, ent_neg_nbr, rel_neg,
      entity_emb, relation_emb, b_gatt, b_agg, ws);
  gru3_kernel<<<ROWS/64, 512, 0, stream>>>(
      gb_his_self, gb_his_path, gb_pos_self, gb_pos_path,
      gb_neg_self, gb_neg_path, entity_emb,
      b_ih, b_hh, b_agg, ws);
  kg2_kernel<<<512, 256, 0, stream>>>(kg_head, kg_rel, kg_tail, kg_tail_neg,
                                      entity_emb, relation_emb, ws);
  kg_reduce_kernel<<<256, 256, 0, stream>>>(ws);
  rsatt_kernel<<<512, 256, 0, stream>>>(W_iatt, b_iatt, ws);
  umlp_kernel<<<512, 256, 0, stream>>>(b_u_mlp, ws, out);
  loss_kernel<<<1, 1024, 0, stream>>>(ws, out);
}

// Round 2
// 864.222 us; speedup vs baseline: 1.9856x; 1.5990x over previous
//
#include <hip/hip_runtime.h>

#define DEV __device__ __forceinline__

#define Dd   64
#define Bb   1024
#define Mm   32
#define Kk   16
#define Ll   8
#define NKGk 65536
#define NH   32768            // B*M
#define ROWS (NH + 2*Bb)      // 34816

// ---- workspace layout (float offsets) ----
#define OFF_WTATT   0          // 64x64  transposed W_tatt
#define OFF_WGS     4096       // 64x64  transposed W_gatt[:, :64]   (WgsT[j*64+d] = W_gatt[d][j])
#define OFF_WCOMB   8192       // 128x64 transposed (W_gatt[:,64:] @ W_re)
#define OFF_WRE     16384      // 128x64 transposed W_re
#define OFF_WAGG    24576      // 128x64 transposed W_agg (WaggT[j*64+d] = W_agg[d][j], j<128)
#define OFF_WU      32768      // 192x64 transposed W_u_mlp
#define OFF_GVEC    45056      // 64     sigmoid(gate)
#define OFF_USERG   45120      // 1024x64
#define OFF_UATT    110656     // 1024x64
#define OFF_SELFH   176192     // 32768x64
#define OFF_HISLC   2273344    // 32768x64
#define OFF_HISGB   4370496    // 32768x64
#define OFF_SELFPN  6467648    // 2x1024x64 (pos, then neg)
#define OFF_LCPN    6598720    // 2x1024x64
#define OFF_GBPN    6729792    // 2x1024x64
#define OFF_ULCPN   6860864    // 2x1024x128
#define OFF_KGSUM   7123008    // 1
#define OFF_KGS     7123012    // 2x65536 kg squared distances (pos, neg)
// GRU packed-weight tables OVERLAY the KGS scratch region: prep writes them,
// gru3 reads them, and only afterwards does kg2 overwrite the region with
// distances (same stream => ordering guaranteed, every launch re-preps).
#define OFF_WIHP    7123072    // 16x8x(4x3x8) = 12288  W_ih packed [jc][w][jj][gate][oi]
#define OFF_WHHP    7135360    // 12288                 W_hh packed, same layout
#define OFF_WAGP    7147648    // 32x8x(4x8)   = 8192   W_agg packed [jc][w][jj][oi]
// Relation-folded tables (round-1): rel vocab is only 65, so the relation half
// of the agg/kg matvecs is precomputed per relation id.
#define OFF_RELC    7155840    // 65x64  (Wcomb_hi @ rel_emb[r])  -> 4160
#define OFF_RELR    7160000    // 65x64  (Wre_hi   @ rel_emb[r])  -> 4160 (end 7164160)

DEV float4 ld4(const float* p){ return *reinterpret_cast<const float4*>(p); }
DEV void st4(float* p, const float4 v){ *reinterpret_cast<float4*>(p) = v; }

DEV float tanh_fast(float x){
  float cx = fminf(15.f, fmaxf(-15.f, x));
  float e = __expf(2.f*cx);
  return __fdividef(e - 1.f, e + 1.f);
}
DEV float sigmoid_fast(float x){ return __fdividef(1.f, 1.f + __expf(-x)); }

// acc[d] += W-row (64 wide) * scalar x, W-row streamed as float4 (LDS: ds_read_b128)
#define MVJ(ACC_, WROW_, XS_) { \
  _Pragma("unroll") for (int d4_ = 0; d4_ < 16; ++d4_){ \
    float4 w_ = *(const float4*)((WROW_) + 4*d4_); \
    ACC_[4*d4_+0] += w_.x*(XS_); ACC_[4*d4_+1] += w_.y*(XS_); \
    ACC_[4*d4_+2] += w_.z*(XS_); ACC_[4*d4_+3] += w_.w*(XS_); } }

// ---------------- prep: weight transposes, Wcomb fold, gate sigmoid, GRU packs, rel tables ----------------
__global__ void prep_kernel(const float* __restrict__ W_tatt, const float* __restrict__ W_gatt,
                            const float* __restrict__ W_re, const float* __restrict__ W_agg,
                            const float* __restrict__ W_u, const float* __restrict__ W_ih,
                            const float* __restrict__ W_hh, const float* __restrict__ gate,
                            const float* __restrict__ relation, float* __restrict__ ws)
{
  int t = threadIdx.x;
  for (int i = t; i < 4096; i += 256){
    int d = i >> 6, j = i & 63;
    ws[OFF_WTATT + j*64 + d] = W_tatt[i];            // W_tatt (64,64)
    ws[OFF_WGS   + j*64 + d] = W_gatt[d*128 + j];    // self half of W_gatt
  }
  for (int i = t; i < 8192; i += 256){
    int j = i >> 6, d = i & 63;
    ws[OFF_WRE  + i] = W_re[d*128 + j];
    ws[OFF_WAGG + i] = W_agg[d*128 + j];
    float s = 0.f;
    for (int dp = 0; dp < 64; ++dp) s += W_gatt[d*128 + 64 + dp] * W_re[dp*128 + j];
    ws[OFF_WCOMB + i] = s;                           // (W_gatt[:,64:] @ W_re)^T
  }
  for (int i = t; i < 12288; i += 256){
    int j = i >> 6, d = i & 63;
    ws[OFF_WU + i] = W_u[d*192 + j];
  }
  // GRU gate-weight pack: linear i = ((jc*8+w)*96) + jj*24 + g*8 + oi ;  j=jc*4+jj, o=g*64+w*8+oi
  for (int i = t; i < 12288; i += 256){
    int jc = i / 768, r1 = i - jc*768;
    int ww = r1 / 96,  r2 = r1 - ww*96;
    int jj = r2 / 24,  r3 = r2 - jj*24;
    int g = r3 >> 3,   oi = r3 & 7;
    int j = jc*4 + jj, o = g*64 + ww*8 + oi;
    ws[OFF_WIHP + i] = W_ih[o*64 + j];
    ws[OFF_WHHP + i] = W_hh[o*64 + j];
  }
  // GRU epilogue W_agg pack: i = ((jc*8+w)*32) + jj*8 + oi ; j=jc*4+jj (0..127), o=w*8+oi
  for (int i = t; i < 8192; i += 256){
    int jc = i >> 8, r1 = i & 255;
    int ww = r1 >> 5, r2 = r1 & 31;
    int jj = r2 >> 3, oi = r2 & 7;
    ws[OFF_WAGP + i] = W_agg[(ww*8 + oi)*128 + jc*4 + jj];
  }
  if (t < 64) ws[OFF_GVEC + t] = sigmoid_fast(gate[t]);
  __syncthreads();   // WCOMB/WRE fully written before folding relation tables
  for (int i = t; i < 4160; i += 256){
    int r = i >> 6, d = i & 63;
    const float* re = relation + r*64;
    float s1 = 0.f, s2 = 0.f;
    for (int j = 0; j < 64; ++j){
      s1 += ws[OFF_WCOMB + (64+j)*64 + d] * re[j];
      s2 += ws[OFF_WRE   + (64+j)*64 + d] * re[j];
    }
    ws[OFF_RELC + i] = s1;
    ws[OFF_RELR + i] = s2;
  }
}

// ---------------- user gather + u_att = relu(user_g @ W_tatt^T + b_tatt) ----------------
__global__ void user_prep_kernel(const int* __restrict__ uidx, const float* __restrict__ user_emb,
                                 const float* __restrict__ b_tatt, float* __restrict__ ws)
{
  int gid = blockIdx.x*256 + threadIdx.x;
  int b = gid >> 6, lane = gid & 63;
  long ui = uidx[b];
  float ugd = user_emb[ui*64 + lane];
  ws[OFF_USERG + b*64 + lane] = ugd;
  const float* WtT = ws + OFF_WTATT;
  float acc = b_tatt[lane];
  for (int j = 0; j < 64; ++j) acc += WtT[j*64 + lane] * __shfl(ugd, j);
  ws[OFF_UATT + b*64 + lane] = fmaxf(acc, 0.f);
}

// ---------------- agg_lc v3: LDS-staged weights, relation table, no xnb regs ----------------
// Round-1 analysis: v2 was latency-bound (VALUBusy 13%, occ 11%): 2048 wave-uniform
// global weight loads per thread on the vector path (no s_load conversion: ws aliasing),
// VGPR 136 (acc[64]+xnb[64]) capping residency at ~3 waves/SIMD. v3:
//  * relation half of the Wcomb matvec folded into RELC[65][64] (prep) -> half the FMA/loads
//  * Wcomb_lo + WgsT staged in LDS (32 KB) -> uniform ds_read_b128 broadcasts, vector path
//    reserved for entity gathers; second stage re-fills LDS with WaggT for the agg phase
//  * xnb[] dropped (neighbor row re-read from L1/L2 in the butterfly) -> VGPR ~95,
//    5 waves/SIMD; LDS 32 KB still allows 5 blocks/CU
__global__ __launch_bounds__(256) void agg2_kernel(
  const int* __restrict__ hS, const int* __restrict__ hN, const int* __restrict__ hR,
  const int* __restrict__ pS, const int* __restrict__ pN, const int* __restrict__ pR,
  const int* __restrict__ nS, const int* __restrict__ nN, const int* __restrict__ nR,
  const float* __restrict__ entity, const float* __restrict__ relation,
  const float* __restrict__ b_gatt, const float* __restrict__ b_agg,
  float* __restrict__ ws)
{
  __shared__ float WL[8192];                // 32 KB: stage1 = [Wcomb_lo | WgsT], stage2 = WaggT
  int tid = threadIdx.x;
  int k = tid & 15, rl = tid >> 4;          // k-lane, row-in-block
  int rbase = blockIdx.x*16;
  const int *sI, *nI, *rI; float *sO, *aO; int nb0, uhis;
  if (rbase < NH)          { sI=hS; nI=hN; rI=hR; sO=ws+OFF_SELFH;        aO=ws+OFF_HISLC;       nb0=rbase;        uhis=1; }
  else if (rbase < NH+Bb)  { sI=pS; nI=pN; rI=pR; sO=ws+OFF_SELFPN;       aO=ws+OFF_LCPN;       nb0=rbase-NH;     uhis=0; }
  else                     { sI=nS; nI=nN; rI=nR; sO=ws+OFF_SELFPN+65536; aO=ws+OFF_LCPN+65536; nb0=rbase-NH-Bb;  uhis=0; }
  int n = nb0 + rl;
  int urow = uhis ? (n >> 5) : n;

  // ---- stage 1: Wcomb low half (4096) + WgsT (4096) ----
  for (int i = tid; i < 1024; i += 256){
    st4(&WL[4*i],        ld4(ws + OFF_WCOMB + 4*i));
    st4(&WL[4096 + 4*i], ld4(ws + OFF_WGS   + 4*i));
  }

  const float* es = entity + (long)sI[n]*64;
  long nbI = nI[n*16 + k], rlI = rI[n*16 + k];
  const float* en = entity + nbI*64;

  // acc initialized from the relation-folded table (65 rows, L1-hot)
  float acc[64];
  {
    const float* rt = ws + OFF_RELC + rlI*64;
    #pragma unroll
    for (int j4 = 0; j4 < 16; ++j4){
      float4 v = ld4(rt + 4*j4);
      acc[4*j4+0] = v.x; acc[4*j4+1] = v.y; acc[4*j4+2] = v.z; acc[4*j4+3] = v.w;
    }
  }
  __syncthreads();                          // WL stage-1 ready

  // ---- sc part: lane owns outputs o = k*4 .. k*4+3 of  sc = b_gatt + Wg_self@self ----
  float4 sc4 = ld4(b_gatt + k*4);
  #pragma unroll 2
  for (int j4 = 0; j4 < 16; ++j4){
    float4 s4 = ld4(es + 4*j4);
    float4 w0 = *(const float4*)&WL[4096 + (4*j4+0)*64 + k*4];
    float4 w1 = *(const float4*)&WL[4096 + (4*j4+1)*64 + k*4];
    float4 w2 = *(const float4*)&WL[4096 + (4*j4+2)*64 + k*4];
    float4 w3 = *(const float4*)&WL[4096 + (4*j4+3)*64 + k*4];
    sc4.x += w0.x*s4.x + w1.x*s4.y + w2.x*s4.z + w3.x*s4.w;
    sc4.y += w0.y*s4.x + w1.y*s4.y + w2.y*s4.z + w3.y*s4.w;
    sc4.z += w0.z*s4.x + w1.z*s4.y + w2.z*s4.z + w3.z*s4.w;
    sc4.w += w0.w*s4.x + w1.w*s4.y + w2.w*s4.z + w3.w*s4.w;
  }
  st4(sO + (long)n*64 + k*4, ld4(es + k*4));

  // ---- neighbor matvec: acc += Wcomb_lo @ nbr  (uniform LDS broadcasts, x prefetched) ----
  {
    float4 x4 = ld4(en);
    #pragma unroll 2
    for (int j4 = 0; j4 < 16; ++j4){
      float4 xn = ld4(en + 4*((j4+1) & 15));   // prefetch next (j4=15 harmlessly reloads 0)
      MVJ(acc, &WL[(4*j4+0)*64], x4.x);
      MVJ(acc, &WL[(4*j4+1)*64], x4.y);
      MVJ(acc, &WL[(4*j4+2)*64], x4.z);
      MVJ(acc, &WL[(4*j4+3)*64], x4.w);
      x4 = xn;
    }
  }

  // ---- logit = u_att . tanh(sc + acc)  (sc broadcast from owner lanes) ----
  int gl = (tid & 63) & 48;                 // group base lane within wave
  const float* up = ws + OFF_UATT + (long)urow*64;
  float lg = 0.f;
  #pragma unroll
  for (int j4 = 0; j4 < 16; ++j4){
    float4 u4 = ld4(up + 4*j4);
    float s0 = __shfl(sc4.x, gl + j4);
    float s1 = __shfl(sc4.y, gl + j4);
    float s2 = __shfl(sc4.z, gl + j4);
    float s3 = __shfl(sc4.w, gl + j4);
    lg += u4.x*tanh_fast(acc[4*j4+0] + s0);
    lg += u4.y*tanh_fast(acc[4*j4+1] + s1);
    lg += u4.z*tanh_fast(acc[4*j4+2] + s2);
    lg += u4.w*tanh_fast(acc[4*j4+3] + s3);
  }
  // ---- softmax over the 16 k-lanes ----
  float mx = lg;
  mx = fmaxf(mx, __shfl_xor(mx, 1)); mx = fmaxf(mx, __shfl_xor(mx, 2));
  mx = fmaxf(mx, __shfl_xor(mx, 4)); mx = fmaxf(mx, __shfl_xor(mx, 8));
  float e = __expf(lg - mx);
  float se = e;
  se += __shfl_xor(se, 1); se += __shfl_xor(se, 2);
  se += __shfl_xor(se, 4); se += __shfl_xor(se, 8);
  float att = __fdividef(e, se);

  // ---- stage 2: WaggT (8192) replaces stage-1 contents ----
  __syncthreads();                          // everyone done reading stage 1
  for (int i = tid; i < 2048; i += 256)
    st4(&WL[4*i], ld4(ws + OFF_WAGG + 4*i));
  __syncthreads();

  // ---- agg: lane computes outputs o = k*4..k*4+3 of tanh(W_agg@[self|new_v]+b) ----
  float4 a4 = ld4(b_agg + k*4);
  #pragma unroll 2
  for (int j4 = 0; j4 < 16; ++j4){          // self half (es now L1-hot)
    float4 s4 = ld4(es + 4*j4);
    float4 w0 = *(const float4*)&WL[(4*j4+0)*64 + k*4];
    float4 w1 = *(const float4*)&WL[(4*j4+1)*64 + k*4];
    float4 w2 = *(const float4*)&WL[(4*j4+2)*64 + k*4];
    float4 w3 = *(const float4*)&WL[(4*j4+3)*64 + k*4];
    a4.x += w0.x*s4.x + w1.x*s4.y + w2.x*s4.z + w3.x*s4.w;
    a4.y += w0.y*s4.x + w1.y*s4.y + w2.y*s4.z + w3.y*s4.w;
    a4.z += w0.z*s4.x + w1.z*s4.y + w2.z*s4.z + w3.z*s4.w;
    a4.w += w0.w*s4.x + w1.w*s4.y + w2.w*s4.z + w3.w*s4.w;
  }
  #pragma unroll 2
  for (int j4 = 0; j4 < 16; ++j4){          // new_v half via 16-lane butterfly (en re-read, L2-hot)
    float4 x4 = ld4(en + 4*j4);
    float xs[4] = {x4.x, x4.y, x4.z, x4.w};
    #pragma unroll
    for (int jj = 0; jj < 4; ++jj){
      float v = att * xs[jj];
      v += __shfl_xor(v, 1); v += __shfl_xor(v, 2);
      v += __shfl_xor(v, 4); v += __shfl_xor(v, 8);
      float4 wv = *(const float4*)&WL[(64 + 4*j4 + jj)*64 + k*4];
      a4.x += wv.x*v; a4.y += wv.y*v; a4.z += wv.z*v; a4.w += wv.w*v;
    }
  }
  float t0 = tanh_fast(a4.x), t1 = tanh_fast(a4.y), t2 = tanh_fast(a4.z), t3 = tanh_fast(a4.w);
  float ss = t0*t0 + t1*t1 + t2*t2 + t3*t3;
  ss += __shfl_xor(ss, 1); ss += __shfl_xor(ss, 2);
  ss += __shfl_xor(ss, 4); ss += __shfl_xor(ss, 8);
  float rn = __fdividef(1.f, fmaxf(sqrtf(ss), 1e-12f));
  float4 o4; o4.x = t0*rn; o4.y = t1*rn; o4.z = t2*rn; o4.w = t3*rn;
  st4(aO + (long)n*64 + k*4, o4);
}

// ---------------- GRU v6: j-outer/i-inner, packed scalar weights, LDS x staging ----------------
__global__ __launch_bounds__(512) void gru3_kernel(
  const int* __restrict__ hS, const int* __restrict__ hP,
  const int* __restrict__ pS, const int* __restrict__ pP,
  const int* __restrict__ nS, const int* __restrict__ nP,
  const float* __restrict__ entity,
  const float* __restrict__ b_ih, const float* __restrict__ b_hh,
  const float* __restrict__ b_agg,
  float* __restrict__ ws)
{
  __shared__ float hb[2][64][65];           // double-buffered h, [buf][dim][row]
  __shared__ float xb[64][65];              // per-t x staging / epilogue self rows, [dim][row]
  int tid = threadIdx.x;
  int w = __builtin_amdgcn_readfirstlane(tid >> 6);   // wave id 0..7 (uniform)
  int lane = tid & 63;                                // lane = row
  int rbase = blockIdx.x*64;
  const int *sIv, *pIv; float* aO; int nb0;
  if (rbase < NH)          { sIv=hS; pIv=hP; aO=ws+OFF_HISGB;        nb0=rbase; }
  else if (rbase < NH+Bb)  { sIv=pS; pIv=pP; aO=ws+OFF_GBPN;        nb0=rbase-NH; }
  else                     { sIv=nS; pIv=nP; aO=ws+OFF_GBPN+65536;  nb0=rbase-NH-Bb; }
  int o0 = w*8;                                       // this wave's output dims o0..o0+7
  const float* WIHP = ws + OFF_WIHP;
  const float* WHHP = ws + OFF_WHHP;
  const float* WAGP = ws + OFF_WAGP;

  float bir[8], biz[8], bin_[8], bhr[8], bhz[8], bhn[8];
  #pragma unroll
  for (int i = 0; i < 8; ++i){
    bir[i] = b_ih[o0+i]; biz[i] = b_ih[64+o0+i]; bin_[i] = b_ih[128+o0+i];
    bhr[i] = b_hh[o0+i]; bhz[i] = b_hh[64+o0+i]; bhn[i]  = b_hh[128+o0+i];
  }

  int pt_next = pIv[(nb0 + lane)*8];        // path index pipelined one t ahead
  #pragma unroll 1
  for (int t = 0; t < 8; ++t){
    const float* ex = entity + (long)pt_next*64 + o0;
    float4 xa = ld4(ex), xc = ld4(ex + 4);
    if (t < 7) pt_next = pIv[(nb0 + lane)*8 + t + 1];

    int cur = t & 1, nxt = cur ^ 1;
    float ahr[8], ahz[8], ahn[8];
    #pragma unroll
    for (int i = 0; i < 8; ++i){ ahr[i] = bhr[i]; ahz[i] = bhz[i]; ahn[i] = bhn[i]; }
    if (t){                                 // h == 0 at t=0: gh = b_hh only
      #pragma unroll 2
      for (int jc = 0; jc < 16; ++jc){
        const float* wp = WHHP + (jc*8 + w)*96;
        float h0 = hb[cur][4*jc+0][lane];
        float h1 = hb[cur][4*jc+1][lane];
        float h2 = hb[cur][4*jc+2][lane];
        float h3 = hb[cur][4*jc+3][lane];
        #pragma unroll
        for (int i = 0; i < 8; ++i){
          ahr[i] += wp[   i]*h0 + wp[24+i]*h1 + wp[48+i]*h2 + wp[72+i]*h3;
          ahz[i] += wp[ 8+i]*h0 + wp[32+i]*h1 + wp[56+i]*h2 + wp[80+i]*h3;
          ahn[i] += wp[16+i]*h0 + wp[40+i]*h1 + wp[64+i]*h2 + wp[88+i]*h3;
        }
      }
    }
    xb[o0+0][lane]=xa.x; xb[o0+1][lane]=xa.y; xb[o0+2][lane]=xa.z; xb[o0+3][lane]=xa.w;
    xb[o0+4][lane]=xc.x; xb[o0+5][lane]=xc.y; xb[o0+6][lane]=xc.z; xb[o0+7][lane]=xc.w;
    __syncthreads();                        // A: xb staged by all waves; hb[cur] reads done

    float air[8], aiz[8], ain[8];
    #pragma unroll
    for (int i = 0; i < 8; ++i){ air[i] = bir[i]; aiz[i] = biz[i]; ain[i] = bin_[i]; }
    #pragma unroll 2
    for (int jc = 0; jc < 16; ++jc){
      const float* wp = WIHP + (jc*8 + w)*96;
      float x0 = xb[4*jc+0][lane];
      float x1 = xb[4*jc+1][lane];
      float x2 = xb[4*jc+2][lane];
      float x3 = xb[4*jc+3][lane];
      #pragma unroll
      for (int i = 0; i < 8; ++i){
        air[i] += wp[   i]*x0 + wp[24+i]*x1 + wp[48+i]*x2 + wp[72+i]*x3;
        aiz[i] += wp[ 8+i]*x0 + wp[32+i]*x1 + wp[56+i]*x2 + wp[80+i]*x3;
        ain[i] += wp[16+i]*x0 + wp[40+i]*x1 + wp[64+i]*x2 + wp[88+i]*x3;
      }
    }
    #pragma unroll
    for (int i = 0; i < 8; ++i){
      float r  = sigmoid_fast(air[i] + ahr[i]);
      float z  = sigmoid_fast(aiz[i] + ahz[i]);
      float nn = tanh_fast(ain[i] + r*ahn[i]);
      float hp = t ? hb[cur][o0+i][lane] : 0.f;
      hb[nxt][o0+i][lane] = (1.f - z)*nn + z*hp;
    }
    __syncthreads();                        // B: h_new ready; xb reads done before next stage
  }

  // ---- epilogue: agg = normalize(tanh(W_agg@[self|hT]+b_agg)); final h is in hb[0] ----
  long si = sIv[nb0 + lane];
  const float* es = entity + si*64 + o0;
  float4 aa = ld4(es), cc = ld4(es + 4);
  float ag[8];
  #pragma unroll
  for (int i = 0; i < 8; ++i) ag[i] = b_agg[o0+i];
  #pragma unroll 2
  for (int jc = 16; jc < 32; ++jc){         // hT half first (hides self gather)
    const float* wp = WAGP + (jc*8 + w)*32;
    float h0 = hb[0][4*(jc-16)+0][lane];
    float h1 = hb[0][4*(jc-16)+1][lane];
    float h2 = hb[0][4*(jc-16)+2][lane];
    float h3 = hb[0][4*(jc-16)+3][lane];
    #pragma unroll
    for (int i = 0; i < 8; ++i)
      ag[i] += wp[i]*h0 + wp[8+i]*h1 + wp[16+i]*h2 + wp[24+i]*h3;
  }
  xb[o0+0][lane]=aa.x; xb[o0+1][lane]=aa.y; xb[o0+2][lane]=aa.z; xb[o0+3][lane]=aa.w;
  xb[o0+4][lane]=cc.x; xb[o0+5][lane]=cc.y; xb[o0+6][lane]=cc.z; xb[o0+7][lane]=cc.w;
  __syncthreads();
  #pragma unroll 2
  for (int jc = 0; jc < 16; ++jc){          // self half
    const float* wp = WAGP + (jc*8 + w)*32;
    float x0 = xb[4*jc+0][lane];
    float x1 = xb[4*jc+1][lane];
    float x2 = xb[4*jc+2][lane];
    float x3 = xb[4*jc+3][lane];
    #pragma unroll
    for (int i = 0; i < 8; ++i)
      ag[i] += wp[i]*x0 + wp[8+i]*x1 + wp[16+i]*x2 + wp[24+i]*x3;
  }
  #pragma unroll
  for (int i = 0; i < 8; ++i) hb[1][o0+i][lane] = tanh_fast(ag[i]);
  __syncthreads();
  int q = tid & 7, r = tid >> 3;
  float vv[8];
  float ss = 0.f;
  #pragma unroll
  for (int jj = 0; jj < 8; ++jj){ float v = hb[1][q*8+jj][r]; vv[jj] = v; ss += v*v; }
  ss += __shfl_xor(ss, 1); ss += __shfl_xor(ss, 2); ss += __shfl_xor(ss, 4);
  float rn = __fdividef(1.f, fmaxf(sqrtf(ss), 1e-12f));
  int n2 = nb0 + r;
  #pragma unroll
  for (int jj4 = 0; jj4 < 2; ++jj4){
    float4 o4; o4.x = vv[4*jj4]*rn; o4.y = vv[4*jj4+1]*rn; o4.z = vv[4*jj4+2]*rn; o4.w = vv[4*jj4+3]*rn;
    st4(aO + (long)n2*64 + q*8 + 4*jj4, o4);
  }
}

// ---------------- KG v3: LDS-staged Wre_lo + relation table ----------------
__global__ __launch_bounds__(256) void kg2_kernel(
  const int* __restrict__ kh, const int* __restrict__ kr,
  const int* __restrict__ kt, const int* __restrict__ ktn,
  const float* __restrict__ entity, const float* __restrict__ relation,
  float* __restrict__ ws)
{
  __shared__ float WL[4096];                // 16 KB: Wre low half
  int tid = threadIdx.x;
  int br = blockIdx.x >> 8;
  int r  = (blockIdx.x & 255)*256 + tid;
  const int* tailI = br ? ktn : kt;
  for (int i = tid; i < 1024; i += 256)
    st4(&WL[4*i], ld4(ws + OFF_WRE + 4*i));

  long rel = kr[r];
  const float* et = entity + (long)tailI[r]*64;
  float acc[64];
  {
    const float* rt = ws + OFF_RELR + rel*64;
    #pragma unroll
    for (int j4 = 0; j4 < 16; ++j4){
      float4 v = ld4(rt + 4*j4);
      acc[4*j4+0] = v.x; acc[4*j4+1] = v.y; acc[4*j4+2] = v.z; acc[4*j4+3] = v.w;
    }
  }
  __syncthreads();
  {
    float4 x4 = ld4(et);
    #pragma unroll 2
    for (int j4 = 0; j4 < 16; ++j4){
      float4 xn = ld4(et + 4*((j4+1) & 15));
      MVJ(acc, &WL[(4*j4+0)*64], x4.x);
      MVJ(acc, &WL[(4*j4+1)*64], x4.y);
      MVJ(acc, &WL[(4*j4+2)*64], x4.z);
      MVJ(acc, &WL[(4*j4+3)*64], x4.w);
      x4 = xn;
    }
  }
  const float* eh = entity + (long)kh[r]*64;
  float s = 0.f;
  #pragma unroll
  for (int j4 = 0; j4 < 16; ++j4){
    float4 h4 = ld4(eh + 4*j4);
    float d0 = h4.x - acc[4*j4+0], d1 = h4.y - acc[4*j4+1];
    float d2 = h4.z - acc[4*j4+2], d3 = h4.w - acc[4*j4+3];
    s += d0*d0 + d1*d1 + d2*d2 + d3*d3;
  }
  ws[OFF_KGS + br*65536 + r] = s;
}

__global__ void kg_reduce_kernel(float* __restrict__ ws)
{
  int r = blockIdx.x*256 + threadIdx.x;
  float s  = ws[OFF_KGS + r];
  float sn = ws[OFF_KGS + 65536 + r];
  float dif = sn - s;
  float ls = fminf(dif, 0.f) - __logf(1.f + __expf(-fabsf(dif)));
  #pragma unroll
  for (int m2 = 1; m2 < 64; m2 <<= 1) ls += __shfl_xor(ls, m2);
  if ((threadIdx.x & 63) == 0) atomicAdd(ws + OFF_KGSUM, ls);
}

// ---------------- rs_att: one wave per (b, branch) ----------------
__global__ void rsatt_kernel(const float* __restrict__ W_iatt, const float* __restrict__ b_iatt,
                             float* __restrict__ ws)
{
  int gid = blockIdx.x*256 + threadIdx.x;
  int gw = gid >> 6, lane = gid & 63;
  int b = gw >> 1, br = gw & 1;
  const float* selfB = ws + OFF_SELFPN + br*65536 + b*64;
  const float* lcB   = ws + OFF_LCPN   + br*65536 + b*64;
  const float* gbB   = ws + OFF_GBPN   + br*65536 + b*64;
  const float* gvec  = ws + OFF_GVEC;
  const float* selfH = ws + OFF_SELFH;
  const float* hisLC = ws + OFF_HISLC;
  const float* hisGB = ws + OFF_HISGB;

  float gd = gvec[lane];
  float sv = selfB[lane], lcv = lcB[lane], gbv = gbB[lane];
  float gated = gd*lcv + (1.f - gd)*gbv;
  float part = W_iatt[128+lane]*sv + W_iatt[192+lane]*gated;
  #pragma unroll
  for (int m2 = 1; m2 < 64; m2 <<= 1) part += __shfl_xor(part, m2);
  float itemdot = part + b_iatt[0];

  int m = lane & 31, half = lane >> 5;
  long nrow = (long)(b*32 + m)*64;
  float sh = 0.f;
  if (half == 0){
    for (int j4 = 0; j4 < 16; ++j4){
      float4 h4 = ld4(selfH + nrow + 4*j4);
      float4 w4 = ld4(W_iatt + 4*j4);
      sh += w4.x*h4.x + w4.y*h4.y + w4.z*h4.z + w4.w*h4.w;
    }
  } else {
    for (int j4 = 0; j4 < 16; ++j4){
      float4 l4 = ld4(hisLC + nrow + 4*j4);
      float4 g4 = ld4(hisGB + nrow + 4*j4);
      float4 gg = ld4(gvec + 4*j4);
      float4 w4 = ld4(W_iatt + 64 + 4*j4);
      sh += w4.x*(gg.x*l4.x + (1.f-gg.x)*g4.x);
      sh += w4.y*(gg.y*l4.y + (1.f-gg.y)*g4.y);
      sh += w4.z*(gg.z*l4.z + (1.f-gg.z)*g4.z);
      sh += w4.w*(gg.w*l4.w + (1.f-gg.w)*g4.w);
    }
  }
  sh += __shfl_xor(sh, 32);
  float logit = tanh_fast(sh + itemdot);
  float mxv = logit;
  #pragma unroll
  for (int m2 = 1; m2 < 32; m2 <<= 1) mxv = fmaxf(mxv, __shfl_xor(mxv, m2));
  float e = __expf(logit - mxv);
  float se = e;
  #pragma unroll
  for (int m2 = 1; m2 < 32; m2 <<= 1) se += __shfl_xor(se, m2);
  float att = __fdividef(e, se);

  float u1 = 0.f, u2 = 0.f;
  for (int mm = 0; mm < 32; ++mm){
    float a = __shfl(att, mm);
    long nr = (long)(b*32 + mm)*64;
    float x1 = selfH[nr + lane];
    float x2 = gd*hisLC[nr + lane] + (1.f - gd)*hisGB[nr + lane];
    u1 += a*x1; u2 += a*x2;
  }
  float* upo = ws + OFF_ULCPN + (long)(br*1024 + b)*128;
  upo[lane] = u1; upo[64 + lane] = u2;
}

// ---------------- u-MLP + score: one wave per (b, branch) ----------------
__global__ void umlp_kernel(const float* __restrict__ b_u, float* __restrict__ ws, float* __restrict__ out)
{
  int gid = blockIdx.x*256 + threadIdx.x;
  int gw = gid >> 6, lane = gid & 63;
  int b = gw >> 1, br = gw & 1;
  const float* WuT = ws + OFF_WU;
  const float* ug  = ws + OFF_USERG + b*64;
  const float* ul  = ws + OFF_ULCPN + (long)(br*1024 + b)*128;
  float acc = b_u[lane];
  for (int j = 0; j < 64; ++j)  acc += WuT[j*64 + lane] * ug[j];
  for (int j = 0; j < 128; ++j) acc += WuT[(64 + j)*64 + lane] * ul[j];
  float uo = fmaxf(acc, 0.f);
  float ssv = uo*uo;
  #pragma unroll
  for (int m2 = 1; m2 < 64; m2 <<= 1) ssv += __shfl_xor(ssv, m2);
  float rn = __fdividef(1.f, fmaxf(sqrtf(ssv), 1e-12f));
  float nuo = uo*rn;
  const float* selfB = ws + OFF_SELFPN + br*65536 + b*64;
  const float* lcB   = ws + OFF_LCPN   + br*65536 + b*64;
  const float* gbB   = ws + OFF_GBPN   + br*65536 + b*64;
  float gd = ws[OFF_GVEC + lane];
  float gated = gd*lcB[lane] + (1.f - gd)*gbB[lane];
  float p = ug[lane]*selfB[lane] + nuo*gated;
  #pragma unroll
  for (int m2 = 1; m2 < 64; m2 <<= 1) p += __shfl_xor(p, m2);
  if (lane == 0) out[br*1024 + b] = p;
}

// ---------------- final loss ----------------
__global__ void loss_kernel(const float* __restrict__ ws, float* __restrict__ out)
{
  __shared__ float red[16];
  int t = threadIdx.x;
  float ps = out[t], ns_ = out[1024 + t];
  float dif = ps - ns_;
  float v = fminf(dif, 0.f) - __logf(1.f + __expf(-fabsf(dif)));
  #pragma unroll
  for (int m2 = 1; m2 < 64; m2 <<= 1) v += __shfl_xor(v, m2);
  if ((t & 63) == 0) red[t >> 6] = v;
  __syncthreads();
  if (t == 0){
    float s = 0.f;
    for (int i = 0; i < 16; ++i) s += red[i];
    float rs = -s * (1.f/1024.f);
    float kg = -ws[OFF_KGSUM] * (1.f/65536.f);
    out[2048] = rs + kg;
  }
}

extern "C" void kernel_launch(void* const* d_in, const int* in_sizes, int n_in,
                              void* d_out, int out_size, void* d_ws, size_t ws_size,
                              hipStream_t stream)
{
  const int* user_indices = (const int*)d_in[0];
  const int* ent_his_self = (const int*)d_in[1];
  const int* ent_his_nbr  = (const int*)d_in[2];
  const int* rel_his      = (const int*)d_in[3];
  const int* ent_pos_self = (const int*)d_in[4];
  const int* ent_pos_nbr  = (const int*)d_in[5];
  const int* rel_pos      = (const int*)d_in[6];
  const int* ent_neg_self = (const int*)d_in[7];
  const int* ent_neg_nbr  = (const int*)d_in[8];
  const int* rel_neg      = (const int*)d_in[9];
  const int* gb_his_self  = (const int*)d_in[10];
  const int* gb_his_path  = (const int*)d_in[11];
  const int* gb_pos_self  = (const int*)d_in[12];
  const int* gb_pos_path  = (const int*)d_in[13];
  const int* gb_neg_self  = (const int*)d_in[14];
  const int* gb_neg_path  = (const int*)d_in[15];
  const int* kg_head      = (const int*)d_in[16];
  const int* kg_rel       = (const int*)d_in[17];
  const int* kg_tail      = (const int*)d_in[18];
  const int* kg_tail_neg  = (const int*)d_in[19];
  const float* entity_emb   = (const float*)d_in[20];
  const float* relation_emb = (const float*)d_in[21];
  const float* user_emb     = (const float*)d_in[22];
  const float* gate         = (const float*)d_in[23];
  const float* W_u_mlp      = (const float*)d_in[24];
  const float* b_u_mlp      = (const float*)d_in[25];
  const float* W_re         = (const float*)d_in[26];
  const float* W_agg        = (const float*)d_in[27];
  const float* b_agg        = (const float*)d_in[28];
  const float* W_gatt       = (const float*)d_in[29];
  const float* b_gatt       = (const float*)d_in[30];
  const float* W_iatt       = (const float*)d_in[31];
  const float* b_iatt       = (const float*)d_in[32];
  const float* W_tatt       = (const float*)d_in[33];
  const float* b_tatt       = (const float*)d_in[34];
  const float* W_ih         = (const float*)d_in[35];
  const float* W_hh         = (const float*)d_in[36];
  const float* b_ih         = (const float*)d_in[37];
  const float* b_hh         = (const float*)d_in[38];
  float* ws  = (float*)d_ws;
  float* out = (float*)d_out;

  (void)hipMemsetAsync(ws + OFF_KGSUM, 0, sizeof(float), stream);
  prep_kernel<<<1, 256, 0, stream>>>(W_tatt, W_gatt, W_re, W_agg, W_u_mlp, W_ih, W_hh, gate,
                                     relation_emb, ws);
  user_prep_kernel<<<256, 256, 0, stream>>>(user_indices, user_emb, b_tatt, ws);
  agg2_kernel<<<ROWS/16, 256, 0, stream>>>(
      ent_his_self, ent_his_nbr, rel_his,
      ent_pos_self, ent_pos_nbr, rel_pos,
      ent_neg_self, ent_neg_nbr, rel_neg,
      entity_emb, relation_emb, b_gatt, b_agg, ws);
  gru3_kernel<<<ROWS/64, 512, 0, stream>>>(
      gb_his_self, gb_his_path, gb_pos_self, gb_pos_path,
      gb_neg_self, gb_neg_path, entity_emb,
      b_ih, b_hh, b_agg, ws);
  kg2_kernel<<<512, 256, 0, stream>>>(kg_head, kg_rel, kg_tail, kg_tail_neg,
                                      entity_emb, relation_emb, ws);
  kg_reduce_kernel<<<256, 256, 0, stream>>>(ws);
  rsatt_kernel<<<512, 256, 0, stream>>>(W_iatt, b_iatt, ws);
  umlp_kernel<<<512, 256, 0, stream>>>(b_u_mlp, ws, out);
  loss_kernel<<<1, 1024, 0, stream>>>(ws, out);
}